// Round 1
// baseline (371.724 us; speedup 1.0000x reference)
//
#include <hip/hip_runtime.h>

// BatchNorm2d training-mode forward, fp32, NCHW.
// B=64, C=256, H=56, W=56. Layout: idx = ((b*C + c)*H + h)*W + w.
// Plane (b,c) is contiguous HW=3136 floats => 784 float4.

#define EPS 1e-5f
constexpr int B_ = 64;
constexpr int C_ = 256;
constexpr int HW_ = 56 * 56;            // 3136
constexpr int HW4_ = HW_ / 4;           // 784
constexpr int NPC_ = B_ * HW_;          // 200704 elements per channel
constexpr unsigned int TOTAL4_ = (unsigned int)B_ * C_ * HW4_;  // 12,845,056 float4s

// ---------------- Kernel 1: per-plane partial sum / sumsq ----------------
// One block per (b,c) plane. plane = b*C + c (planes are contiguous in memory).
__global__ void __launch_bounds__(256) bn_partial(const float* __restrict__ x,
                                                  float* __restrict__ psum,
                                                  float* __restrict__ psumsq) {
    const int plane = blockIdx.x;                       // 0 .. B*C-1
    const float4* xp = (const float4*)(x + (size_t)plane * HW_);

    float s = 0.f, ss = 0.f;
    for (int i = threadIdx.x; i < HW4_; i += 256) {
        float4 v = xp[i];
        s  += v.x + v.y + v.z + v.w;
        ss += v.x * v.x + v.y * v.y + v.z * v.z + v.w * v.w;
    }

    // wave-64 reduce
    for (int off = 32; off > 0; off >>= 1) {
        s  += __shfl_down(s, off);
        ss += __shfl_down(ss, off);
    }
    __shared__ float ls[8];
    const int wave = threadIdx.x >> 6;
    const int lane = threadIdx.x & 63;
    if (lane == 0) { ls[wave] = s; ls[4 + wave] = ss; }
    __syncthreads();
    if (threadIdx.x == 0) {
        float S  = ls[0] + ls[1] + ls[2] + ls[3];
        float SS = ls[4] + ls[5] + ls[6] + ls[7];
        const int b = plane / C_;
        const int c = plane % C_;
        // transpose so channel's 64 partials are contiguous for kernel 2
        psum[c * B_ + b]   = S;
        psumsq[c * B_ + b] = SS;
    }
}

// ---------------- Kernel 2: per-channel finalize -> scale/shift ----------------
// grid = C blocks, 64 threads (one wave) each.
__global__ void __launch_bounds__(64) bn_finalize(const float* __restrict__ psum,
                                                  const float* __restrict__ psumsq,
                                                  const float* __restrict__ gamma,
                                                  const float* __restrict__ beta,
                                                  float* __restrict__ scale,
                                                  float* __restrict__ shift) {
    const int c = blockIdx.x;
    const int t = threadIdx.x;   // 0..63
    float s  = psum[c * B_ + t];
    float ss = psumsq[c * B_ + t];
    for (int off = 32; off > 0; off >>= 1) {
        s  += __shfl_down(s, off);
        ss += __shfl_down(ss, off);
    }
    if (t == 0) {
        const float invN = 1.0f / (float)NPC_;
        float mean = s * invN;
        float var  = ss * invN - mean * mean;
        float sc   = gamma[c] * rsqrtf(var + EPS);
        scale[c] = sc;
        shift[c] = beta[c] - mean * sc;
    }
}

// ---------------- Kernel 3: elementwise apply ----------------
__global__ void __launch_bounds__(256) bn_apply(const float* __restrict__ x,
                                                const float* __restrict__ scale,
                                                const float* __restrict__ shift,
                                                float* __restrict__ out) {
    const unsigned int i = blockIdx.x * 256u + threadIdx.x;   // float4 index
    if (i >= TOTAL4_) return;
    // all 4 elements share a channel since HW4_=784 divides plane evenly
    const int c = (int)((i / (unsigned int)HW4_) % (unsigned int)C_);
    float4 v = ((const float4*)x)[i];
    const float sc = scale[c];
    const float sh = shift[c];
    float4 o;
    o.x = v.x * sc + sh;
    o.y = v.y * sc + sh;
    o.z = v.z * sc + sh;
    o.w = v.w * sc + sh;
    ((float4*)out)[i] = o;
}

extern "C" void kernel_launch(void* const* d_in, const int* in_sizes, int n_in,
                              void* d_out, int out_size, void* d_ws, size_t ws_size,
                              hipStream_t stream) {
    const float* x     = (const float*)d_in[0];
    const float* gamma = (const float*)d_in[1];
    const float* beta  = (const float*)d_in[2];
    float* out = (float*)d_out;

    // workspace layout (floats): psum[B*C] | psumsq[B*C] | scale[C] | shift[C]
    float* psum   = (float*)d_ws;
    float* psumsq = psum + B_ * C_;
    float* scale  = psumsq + B_ * C_;
    float* shift  = scale + C_;

    bn_partial<<<B_ * C_, 256, 0, stream>>>(x, psum, psumsq);
    bn_finalize<<<C_, 64, 0, stream>>>(psum, psumsq, gamma, beta, scale, shift);
    const unsigned int nblk = (TOTAL4_ + 255u) / 256u;
    bn_apply<<<nblk, 256, 0, stream>>>(x, scale, shift, out);
}